// Round 1
// baseline (324.505 us; speedup 1.0000x reference)
//
#include <hip/hip_runtime.h>
#include <hip/hip_bf16.h>

typedef __attribute__((ext_vector_type(8))) short short8;
typedef __attribute__((ext_vector_type(4))) float f32x4;
typedef __attribute__((ext_vector_type(4))) unsigned int u32x4;
typedef unsigned short u16;

static constexpr int BATCH = 8;
static constexpr int NDIM  = 2048;   // rows of A / rows of C
static constexpr int MDIM  = 2048;   // rows of B / cols of C
static constexpr int EDIM  = 1024;   // reduction dim
static constexpr int BM    = 128;    // C-rows per block
static constexpr int BN    = 128;    // C-cols per block
static constexpr int BK    = 32;
static constexpr int KIT   = EDIM / BK;  // 32
static constexpr int LSTR  = 40;     // LDS row stride (u16): 80 B -> conflict-light, 16B-aligned

// pack two f32 -> two bf16 (truncation) in one v_perm_b32
__device__ __forceinline__ unsigned pk(float lo, float hi) {
  return __builtin_amdgcn_perm(__float_as_uint(hi), __float_as_uint(lo), 0x07060302u);
}
__device__ __forceinline__ u32x4 pack8(f32x4 x, f32x4 y) {
  u32x4 r;
  r[0] = pk(x[0], x[1]); r[1] = pk(x[2], x[3]);
  r[2] = pk(y[0], y[1]); r[3] = pk(y[2], y[3]);
  return r;
}

__global__ __launch_bounds__(256, 3)
void bmm_bt_kernel(const float* __restrict__ A, const float* __restrict__ B,
                   float* __restrict__ C) {
  __shared__ u16 As[BM * LSTR];
  __shared__ u16 Bs[BN * LSTR];

  const int tid  = threadIdx.x;
  const int lane = tid & 63;
  const int wave = tid >> 6;
  const int quad = lane >> 4;
  const int ml   = lane & 15;
  const int wrow = (wave >> 1) * 64;   // wave's 64x64 quadrant
  const int wcol = (wave & 1) * 64;

  const int tcol  = blockIdx.x;   // tile along M
  const int trow  = blockIdx.y;   // tile along N
  const int batch = blockIdx.z;

  const float* Ab = A + (size_t)batch * NDIM * EDIM + (size_t)trow * BM * EDIM;
  const float* Bb = B + (size_t)batch * MDIM * EDIM + (size_t)tcol * BN * EDIM;
  float*       Cb = C + (size_t)batch * NDIM * MDIM;

  // staging decomposition: unit u in [0,512): row = u>>2, 8 floats at col (u&3)*8
  const int r0 = tid >> 2;
  const int p0 = (tid & 3) * 8;
  const int r1 = r0 + 64;             // second unit (u = tid + 256)

  const float* pA0 = Ab + (size_t)r0 * EDIM + p0;
  const float* pA1 = Ab + (size_t)r1 * EDIM + p0;
  const float* pB0 = Bb + (size_t)r0 * EDIM + p0;
  const float* pB1 = Bb + (size_t)r1 * EDIM + p0;

  u16* wA0 = &As[r0 * LSTR + p0];
  u16* wA1 = &As[r1 * LSTR + p0];
  u16* wB0 = &Bs[r0 * LSTR + p0];
  u16* wB1 = &Bs[r1 * LSTR + p0];

  // prologue: loads for kb = 0
  f32x4 a0 = *(const f32x4*)(pA0);
  f32x4 a1 = *(const f32x4*)(pA0 + 4);
  f32x4 a2 = *(const f32x4*)(pA1);
  f32x4 a3 = *(const f32x4*)(pA1 + 4);
  f32x4 b0 = *(const f32x4*)(pB0);
  f32x4 b1 = *(const f32x4*)(pB0 + 4);
  f32x4 b2 = *(const f32x4*)(pB1);
  f32x4 b3 = *(const f32x4*)(pB1 + 4);

  f32x4 acc[4][4] = {};

  for (int kb = 0; kb < KIT; ++kb) {
    __syncthreads();                       // prior iter done reading LDS
    *(u32x4*)wA0 = pack8(a0, a1);
    *(u32x4*)wA1 = pack8(a2, a3);
    *(u32x4*)wB0 = pack8(b0, b1);
    *(u32x4*)wB1 = pack8(b2, b3);
    __syncthreads();

    // prefetch next K-slab into registers (overlaps with MFMA below)
    if (kb + 1 < KIT) {
      const int off = (kb + 1) * BK;
      a0 = *(const f32x4*)(pA0 + off);
      a1 = *(const f32x4*)(pA0 + off + 4);
      a2 = *(const f32x4*)(pA1 + off);
      a3 = *(const f32x4*)(pA1 + off + 4);
      b0 = *(const f32x4*)(pB0 + off);
      b1 = *(const f32x4*)(pB0 + off + 4);
      b2 = *(const f32x4*)(pB1 + off);
      b3 = *(const f32x4*)(pB1 + off + 4);
    }

    short8 af[4], bfr[4];
#pragma unroll
    for (int i = 0; i < 4; ++i)
      af[i] = *(const short8*)&As[(wrow + i * 16 + ml) * LSTR + quad * 8];
#pragma unroll
    for (int i = 0; i < 4; ++i)
      bfr[i] = *(const short8*)&Bs[(wcol + i * 16 + ml) * LSTR + quad * 8];

#pragma unroll
    for (int mi = 0; mi < 4; ++mi)
#pragma unroll
      for (int ni = 0; ni < 4; ++ni)
        acc[mi][ni] = __builtin_amdgcn_mfma_f32_16x16x32_bf16(
            af[mi], bfr[ni], acc[mi][ni], 0, 0, 0);
  }

  // epilogue: C/D layout col = lane&15, row = quad*4 + reg
  const int crow = trow * BM + wrow + quad * 4;
  const int ccol = tcol * BN + wcol + ml;
#pragma unroll
  for (int mi = 0; mi < 4; ++mi) {
#pragma unroll
    for (int ni = 0; ni < 4; ++ni) {
      float* cp = Cb + (size_t)(crow + mi * 16) * MDIM + (ccol + ni * 16);
#pragma unroll
      for (int r = 0; r < 4; ++r)
        cp[(size_t)r * MDIM] = acc[mi][ni][r];
    }
  }
}

extern "C" void kernel_launch(void* const* d_in, const int* in_sizes, int n_in,
                              void* d_out, int out_size, void* d_ws, size_t ws_size,
                              hipStream_t stream) {
  const float* A = (const float*)d_in[0];
  const float* B = (const float*)d_in[1];
  float*       C = (float*)d_out;
  dim3 grid(MDIM / BN, NDIM / BM, BATCH);
  bmm_bt_kernel<<<grid, dim3(256), 0, stream>>>(A, B, C);
}

// Round 2
// 301.639 us; speedup vs baseline: 1.0758x; 1.0758x over previous
//
#include <hip/hip_runtime.h>
#include <hip/hip_bf16.h>

typedef __attribute__((ext_vector_type(8))) short short8;
typedef __attribute__((ext_vector_type(4))) float f32x4;
typedef __attribute__((ext_vector_type(4))) unsigned int u32x4;
typedef unsigned short u16;
typedef __attribute__((address_space(1))) void gvoid;
typedef __attribute__((address_space(3))) void lvoid;

static constexpr int BATCH = 8;
static constexpr int NDIM  = 2048;
static constexpr int MDIM  = 2048;
static constexpr int EDIM  = 1024;
static constexpr int BM    = 128;
static constexpr int BN    = 128;
static constexpr int BK    = 32;
static constexpr int KIT   = EDIM / BK;  // 32

// ---------------- phase 1: fp32 -> bf16 (RNE) ----------------
__device__ __forceinline__ unsigned bf16rne_pair(float a, float b) {
  unsigned ua = __float_as_uint(a), ub = __float_as_uint(b);
  ua = (ua + 0x7FFFu + ((ua >> 16) & 1u)) >> 16;
  ub = (ub + 0x7FFFu + ((ub >> 16) & 1u)) >> 16;
  return ua | (ub << 16);
}

__global__ __launch_bounds__(256)
void cvt_kernel(const float* __restrict__ A, const float* __restrict__ B,
                u16* __restrict__ Abf, u16* __restrict__ Bbf) {
  const int half = (BATCH * NDIM * EDIM) / (256 * 8);  // 8192 blocks per matrix
  int bid = blockIdx.x;
  const float* src; u16* dst;
  if (bid < half) { src = A; dst = Abf; }
  else            { src = B; dst = Bbf; bid -= half; }
  size_t idx = ((size_t)bid * 256 + threadIdx.x) * 8;
  f32x4 x = *(const f32x4*)(src + idx);
  f32x4 y = *(const f32x4*)(src + idx + 4);
  u32x4 r;
  r[0] = bf16rne_pair(x[0], x[1]);
  r[1] = bf16rne_pair(x[2], x[3]);
  r[2] = bf16rne_pair(y[0], y[1]);
  r[3] = bf16rne_pair(y[2], y[3]);
  *(u32x4*)(dst + idx) = r;
}

// ---------------- phase 2: m97-structure bf16 GEMM ----------------
__device__ __forceinline__ void async_cp16(const void* g, void* l) {
  __builtin_amdgcn_global_load_lds((gvoid*)g, (lvoid*)l, 16, 0, 0);
}

__global__ __launch_bounds__(256, 3)
void bmm_bf16_kernel(const u16* __restrict__ A, const u16* __restrict__ B,
                     float* __restrict__ C) {
  // unpadded row-major: global_load_lds requires contiguous lane order (no pad)
  __shared__ u16 As[BM * BK];
  __shared__ u16 Bs[BN * BK];

  const int tid  = threadIdx.x;
  const int lane = tid & 63;
  const int wave = tid >> 6;
  const int quad = lane >> 4;
  const int ml   = lane & 15;
  const int wrow = (wave >> 1) * 64;
  const int wcol = (wave & 1) * 64;

  const int tcol  = blockIdx.x;
  const int trow  = blockIdx.y;
  const int batch = blockIdx.z;

  const u16* Ab = A + (size_t)batch * NDIM * EDIM + (size_t)trow * BM * EDIM;
  const u16* Bb = B + (size_t)batch * MDIM * EDIM + (size_t)tcol * BN * EDIM;
  float*     Cb = C + (size_t)batch * NDIM * MDIM;

  // staging: 8 wave-instructions cover 128 rows x 32 bf16 (64 B/row).
  // wave w, instr j: rows [w*16 + j*64, +16); lane covers row base+lane/4,
  // 16 B chunk (lane%4)*8 elements. LDS dest = base + lane*16 (contiguous).
  const int rA0 = wave * 16;         // j=0
  const int rA1 = wave * 16 + 64;    // j=1
  const int lrow = lane >> 2;
  const int lcol = (lane & 3) * 8;

  const u16* gA0 = Ab + (size_t)(rA0 + lrow) * EDIM + lcol;
  const u16* gA1 = Ab + (size_t)(rA1 + lrow) * EDIM + lcol;
  const u16* gB0 = Bb + (size_t)(rA0 + lrow) * EDIM + lcol;
  const u16* gB1 = Bb + (size_t)(rA1 + lrow) * EDIM + lcol;
  u16* lA0 = &As[rA0 * BK];
  u16* lA1 = &As[rA1 * BK];
  u16* lB0 = &Bs[rA0 * BK];
  u16* lB1 = &Bs[rA1 * BK];

  f32x4 acc[4][4] = {};

  for (int kb = 0; kb < KIT; ++kb) {
    const int ko = kb * BK;
    __syncthreads();                 // previous tile's LDS reads complete
    async_cp16(gA0 + ko, lA0);
    async_cp16(gA1 + ko, lA1);
    async_cp16(gB0 + ko, lB0);
    async_cp16(gB1 + ko, lB1);
    __syncthreads();                 // vmcnt(0) drain + barrier

    short8 af[4], bfr[4];
#pragma unroll
    for (int i = 0; i < 4; ++i)
      af[i] = *(const short8*)&As[(wrow + i * 16 + ml) * BK + quad * 8];
#pragma unroll
    for (int i = 0; i < 4; ++i)
      bfr[i] = *(const short8*)&Bs[(wcol + i * 16 + ml) * BK + quad * 8];

#pragma unroll
    for (int mi = 0; mi < 4; ++mi)
#pragma unroll
      for (int ni = 0; ni < 4; ++ni)
        acc[mi][ni] = __builtin_amdgcn_mfma_f32_16x16x32_bf16(
            af[mi], bfr[ni], acc[mi][ni], 0, 0, 0);
  }

  const int crow = trow * BM + wrow + quad * 4;
  const int ccol = tcol * BN + wcol + ml;
#pragma unroll
  for (int mi = 0; mi < 4; ++mi) {
#pragma unroll
    for (int ni = 0; ni < 4; ++ni) {
      float* cp = Cb + (size_t)(crow + mi * 16) * MDIM + (ccol + ni * 16);
#pragma unroll
      for (int r = 0; r < 4; ++r)
        cp[(size_t)r * MDIM] = acc[mi][ni][r];
    }
  }
}

// ---------------- fallback (R1 kernel): fused fp32->bf16 staging ----------------
static constexpr int LSTR = 40;

__device__ __forceinline__ unsigned pk(float lo, float hi) {
  return __builtin_amdgcn_perm(__float_as_uint(hi), __float_as_uint(lo), 0x07060302u);
}
__device__ __forceinline__ u32x4 pack8(f32x4 x, f32x4 y) {
  u32x4 r;
  r[0] = pk(x[0], x[1]); r[1] = pk(x[2], x[3]);
  r[2] = pk(y[0], y[1]); r[3] = pk(y[2], y[3]);
  return r;
}

__global__ __launch_bounds__(256, 3)
void bmm_bt_kernel(const float* __restrict__ A, const float* __restrict__ B,
                   float* __restrict__ C) {
  __shared__ u16 As[BM * LSTR];
  __shared__ u16 Bs[BN * LSTR];

  const int tid  = threadIdx.x;
  const int lane = tid & 63;
  const int wave = tid >> 6;
  const int quad = lane >> 4;
  const int ml   = lane & 15;
  const int wrow = (wave >> 1) * 64;
  const int wcol = (wave & 1) * 64;

  const int tcol  = blockIdx.x;
  const int trow  = blockIdx.y;
  const int batch = blockIdx.z;

  const float* Ab = A + (size_t)batch * NDIM * EDIM + (size_t)trow * BM * EDIM;
  const float* Bb = B + (size_t)batch * MDIM * EDIM + (size_t)tcol * BN * EDIM;
  float*       Cb = C + (size_t)batch * NDIM * MDIM;

  const int r0 = tid >> 2;
  const int p0 = (tid & 3) * 8;
  const int r1 = r0 + 64;

  const float* pA0 = Ab + (size_t)r0 * EDIM + p0;
  const float* pA1 = Ab + (size_t)r1 * EDIM + p0;
  const float* pB0 = Bb + (size_t)r0 * EDIM + p0;
  const float* pB1 = Bb + (size_t)r1 * EDIM + p0;

  u16* wA0 = &As[r0 * LSTR + p0];
  u16* wA1 = &As[r1 * LSTR + p0];
  u16* wB0 = &Bs[r0 * LSTR + p0];
  u16* wB1 = &Bs[r1 * LSTR + p0];

  f32x4 a0 = *(const f32x4*)(pA0);
  f32x4 a1 = *(const f32x4*)(pA0 + 4);
  f32x4 a2 = *(const f32x4*)(pA1);
  f32x4 a3 = *(const f32x4*)(pA1 + 4);
  f32x4 b0 = *(const f32x4*)(pB0);
  f32x4 b1 = *(const f32x4*)(pB0 + 4);
  f32x4 b2 = *(const f32x4*)(pB1);
  f32x4 b3 = *(const f32x4*)(pB1 + 4);

  f32x4 acc[4][4] = {};

  for (int kb = 0; kb < KIT; ++kb) {
    __syncthreads();
    *(u32x4*)wA0 = pack8(a0, a1);
    *(u32x4*)wA1 = pack8(a2, a3);
    *(u32x4*)wB0 = pack8(b0, b1);
    *(u32x4*)wB1 = pack8(b2, b3);
    __syncthreads();

    if (kb + 1 < KIT) {
      const int off = (kb + 1) * BK;
      a0 = *(const f32x4*)(pA0 + off);
      a1 = *(const f32x4*)(pA0 + off + 4);
      a2 = *(const f32x4*)(pA1 + off);
      a3 = *(const f32x4*)(pA1 + off + 4);
      b0 = *(const f32x4*)(pB0 + off);
      b1 = *(const f32x4*)(pB0 + off + 4);
      b2 = *(const f32x4*)(pB1 + off);
      b3 = *(const f32x4*)(pB1 + off + 4);
    }

    short8 af[4], bfr[4];
#pragma unroll
    for (int i = 0; i < 4; ++i)
      af[i] = *(const short8*)&As[(wrow + i * 16 + ml) * LSTR + quad * 8];
#pragma unroll
    for (int i = 0; i < 4; ++i)
      bfr[i] = *(const short8*)&Bs[(wcol + i * 16 + ml) * LSTR + quad * 8];

#pragma unroll
    for (int mi = 0; mi < 4; ++mi)
#pragma unroll
      for (int ni = 0; ni < 4; ++ni)
        acc[mi][ni] = __builtin_amdgcn_mfma_f32_16x16x32_bf16(
            af[mi], bfr[ni], acc[mi][ni], 0, 0, 0);
  }

  const int crow = trow * BM + wrow + quad * 4;
  const int ccol = tcol * BN + wcol + ml;
#pragma unroll
  for (int mi = 0; mi < 4; ++mi) {
#pragma unroll
    for (int ni = 0; ni < 4; ++ni) {
      float* cp = Cb + (size_t)(crow + mi * 16) * MDIM + (ccol + ni * 16);
#pragma unroll
      for (int r = 0; r < 4; ++r)
        cp[(size_t)r * MDIM] = acc[mi][ni][r];
    }
  }
}

extern "C" void kernel_launch(void* const* d_in, const int* in_sizes, int n_in,
                              void* d_out, int out_size, void* d_ws, size_t ws_size,
                              hipStream_t stream) {
  const float* A = (const float*)d_in[0];
  const float* B = (const float*)d_in[1];
  float*       C = (float*)d_out;

  const size_t elems = (size_t)BATCH * NDIM * EDIM;      // per matrix
  const size_t need  = 2 * elems * sizeof(u16);          // 64 MiB

  if (ws_size >= need) {
    u16* Abf = (u16*)d_ws;
    u16* Bbf = Abf + elems;
    const int cvt_blocks = (int)(2 * elems / (256 * 8)); // 16384
    cvt_kernel<<<cvt_blocks, 256, 0, stream>>>(A, B, Abf, Bbf);
    dim3 grid(MDIM / BN, NDIM / BM, BATCH);
    bmm_bf16_kernel<<<grid, dim3(256), 0, stream>>>(Abf, Bbf, C);
  } else {
    dim3 grid(MDIM / BN, NDIM / BM, BATCH);
    bmm_bt_kernel<<<grid, dim3(256), 0, stream>>>(A, B, C);
  }
}